// Round 4
// baseline (677.208 us; speedup 1.0000x reference)
//
#include <hip/hip_runtime.h>
#include <math.h>

#define H_ 2048
#define W_ 2448
#define HW (H_*W_)          // 5013504
#define HW2 (HW/2)          // 2506752 = 9792 * 256 exactly

typedef float f2 __attribute__((ext_vector_type(2)));
typedef float f4 __attribute__((ext_vector_type(4)));

// f32-exact einsum coefficients (sin/cos evaluated at f32-rounded 2*pi*k/4):
#define SIN2_C  (-8.7422777e-08f)   // sin(pi_f32)
#define COS1_C  (-4.3711388e-08f)   // cos(pi/2_f32)
#define COS3_C  ( 1.1924881e-08f)   // cos(3pi/2_f32)
#define TWO_PI_F   6.2831854820251465f
#define PI_HALF_F  1.5707963705062866f   // f32(pi/2)
#define PI3HALF_F  4.7123889923095703f   // f32(3*pi/2)
#define SCALE_F    2.5464790894703254f   // f32(16/(2*pi))
#define BG_THR_F   0.05f

// ROUND-4 DIAGNOSTIC BUILD: body identical to round 3 (best measured).
// kernel_launch enqueues the kernel TWICE (idempotent -> correctness
// unaffected). Delta(dur_us) vs round 3's 593.5 measures the kernel's TRUE
// duration, which the top-5 dispatch table has never shown (all slots taken
// by the harness's ~297 us poison fills). This decomposition decides whether
// the kernel is ~294 us (attack it) or ~145 us (near handicapped roofline).

__global__ __launch_bounds__(256, 4)
void cg_kernel(const float* __restrict__ img, f4* __restrict__ out4) {
    const int t = blockIdx.x * 256 + threadIdx.x;   // grid covers HW2 exactly
    const f2* in2 = (const f2*)img;

    f2 p[8];
#pragma unroll
    for (int i = 0; i < 8; ++i)
        p[i] = __builtin_nontemporal_load(&in2[(size_t)i * HW2 + t]);
    f2 g[16];
#pragma unroll
    for (int i = 0; i < 16; ++i)
        g[i] = __builtin_nontemporal_load(&in2[(size_t)(8 + i) * HW2 + t]);

    float col[2], row[2];
#pragma unroll
    for (int j = 0; j < 2; ++j) {
        const float i0 = p[0][j], i1 = p[1][j], i2 = p[2][j], i3 = p[3][j];
        const float i4 = p[4][j], i5 = p[5][j], i6 = p[6][j], i7 = p[7][j];

        // s = i1 + SIN2*i2 - i3 ; c = ((i0 + COS1*i1) - i2) + COS3*i3
        // non-fused f32 ops: comparisons downstream are tie-sensitive
        float sc = __fsub_rn(__fadd_rn(i1, __fmul_rn(SIN2_C, i2)), i3);
        float cc = __fadd_rn(__fsub_rn(__fadd_rn(i0, __fmul_rn(COS1_C, i1)), i2),
                             __fmul_rn(COS3_C, i3));
        float sr = __fsub_rn(__fadd_rn(i5, __fmul_rn(SIN2_C, i6)), i7);
        float cr = __fadd_rn(__fsub_rn(__fadd_rn(i4, __fmul_rn(COS1_C, i5)), i6),
                             __fmul_rn(COS3_C, i7));

        float bgc = __fmul_rn(0.5f, __fsqrt_rn(__fadd_rn(__fmul_rn(sc, sc), __fmul_rn(cc, cc))));
        float bgr = __fmul_rn(0.5f, __fsqrt_rn(__fadd_rn(__fmul_rn(sr, sr), __fmul_rn(cr, cr))));
        float msk = (bgc > BG_THR_F || bgr > BG_THR_F) ? 1.0f : 0.0f;

        // pairwise (np-style) mean of the 8 phase-shift planes
        float thr = __fmul_rn(0.125f,
            __fadd_rn(__fadd_rn(__fadd_rn(i0, i1), __fadd_rn(i2, i3)),
                      __fadd_rn(__fadd_rn(i4, i5), __fadd_rn(i6, i7))));

        float psc = -atan2f(sc, cc);
        if (psc < 0.0f) psc = __fadd_rn(psc, TWO_PI_F);
        float psr = -atan2f(sr, cr);
        if (psr < 0.0f) psr = __fadd_rn(psr, TWO_PI_F);

        // graycode cumulative-XOR decode, ratio = {128,...,1}
        int cumc = 0, v2c = 0, k1c = 0;
        int cumr = 0, v2r = 0, k1r = 0;
#pragma unroll
        for (int i = 0; i < 8; ++i) {
            cumc ^= (g[i][j]     > thr) ? 1 : 0;
            cumr ^= (g[8 + i][j] > thr) ? 1 : 0;
            v2c += cumc << (7 - i);
            v2r += cumr << (7 - i);
            if (i < 7) { k1c += cumc << (6 - i); k1r += cumr << (6 - i); }
        }
        int k2c = (v2c + 1) >> 1;
        int k2r = (v2r + 1) >> 1;

        float ac;
        if (psc <= PI_HALF_F)      ac = __fmul_rn(TWO_PI_F, (float)k2c);
        else if (psc < PI3HALF_F)  ac = __fmul_rn(TWO_PI_F, (float)k1c);
        else                       ac = __fsub_rn(__fmul_rn(TWO_PI_F, (float)k2c), TWO_PI_F);
        float ar;
        if (psr <= PI_HALF_F)      ar = __fmul_rn(TWO_PI_F, (float)k2r);
        else if (psr < PI3HALF_F)  ar = __fmul_rn(TWO_PI_F, (float)k1r);
        else                       ar = __fsub_rn(__fmul_rn(TWO_PI_F, (float)k2r), TWO_PI_F);

        psc = __fadd_rn(psc, ac);
        psr = __fadd_rn(psr, ar);

        col[j] = __fmul_rn(__fmul_rn(psc, msk), SCALE_F);
        row[j] = __fmul_rn(__fmul_rn(psr, msk), SCALE_F);
    }

    // pixels 2t, 2t+1 -> out floats [4t .. 4t+3] == out4[t]
    f4 o = {col[0], row[0], col[1], row[1]};
    __builtin_nontemporal_store(o, &out4[t]);
}

extern "C" void kernel_launch(void* const* d_in, const int* in_sizes, int n_in,
                              void* d_out, int out_size, void* d_ws, size_t ws_size,
                              hipStream_t stream) {
    const float* img = (const float*)d_in[0];
    f4* out = (f4*)d_out;
    dim3 grid(HW2 / 256), block(256);   // 9792 blocks
    // DIAGNOSTIC: launch twice. Second launch recomputes the identical
    // output (input unmodified) -> passes verification; Delta(dur_us)
    // vs the single-launch round isolates the kernel's true duration.
    hipLaunchKernelGGL(cg_kernel, grid, block, 0, stream, img, out);
    hipLaunchKernelGGL(cg_kernel, grid, block, 0, stream, img, out);
}

// Round 5
// 588.566 us; speedup vs baseline: 1.1506x; 1.1506x over previous
//
#include <hip/hip_runtime.h>
#include <math.h>

#define H_ 2048
#define W_ 2448
#define HW (H_*W_)          // 5013504
#define HW2 (HW/2)          // 2506752 = 9792 * 256 exactly

typedef float f2 __attribute__((ext_vector_type(2)));
typedef float f4 __attribute__((ext_vector_type(4)));

// f32-exact einsum coefficients (sin/cos evaluated at f32-rounded 2*pi*k/4):
//   delta_f32 = {0, 1.5707964f, 3.1415927f, 4.7123890f}
//   sin = {0, 1, -8.742278e-8, -1},  cos = {1, -4.3711388e-8, -1, +1.1924881e-8}
#define SIN2_C  (-8.7422777e-08f)   // sin(pi_f32)
#define COS1_C  (-4.3711388e-08f)   // cos(pi/2_f32)
#define COS3_C  ( 1.1924881e-08f)   // cos(3pi/2_f32)
#define TWO_PI_F   6.2831854820251465f
#define PI_HALF_F  1.5707963705062866f   // f32(pi/2)
#define PI3HALF_F  4.7123889923095703f   // f32(3*pi/2)
#define SCALE_F    2.5464790894703254f   // f32(16/(2*pi))
#define BG_THR_F   0.05f

// FINAL KERNEL — at the HBM roofline.
// Round-4 double-launch diagnostic measured the kernel's true duration:
// Delta(dur) = 677.21 - 593.52 = 83.7 us for 521.4 MB of compulsory traffic
// = 6.23 TB/s = 99% of the measured-achievable 6.29 TB/s ceiling.
// The remaining ~510 us of dur_us is harness reset work (1.925 GB poison
// fill ~297 us + input restore), outside kernel control.
// Config notes (measured): nt load/store helps (+25 us kernel penalty
// without it — L2/L3 pollution from 481 MB stream-once data); access
// pattern (24-concurrent vs sequential bursts) and occupancy (f4 vs f2
// footprint) are neutral — the read path is saturated either way.

__global__ __launch_bounds__(256, 4)
void cg_kernel(const float* __restrict__ img, f4* __restrict__ out4) {
    const int t = blockIdx.x * 256 + threadIdx.x;   // grid covers HW2 exactly
    const f2* in2 = (const f2*)img;

    f2 p[8];
#pragma unroll
    for (int i = 0; i < 8; ++i)
        p[i] = __builtin_nontemporal_load(&in2[(size_t)i * HW2 + t]);
    f2 g[16];
#pragma unroll
    for (int i = 0; i < 16; ++i)
        g[i] = __builtin_nontemporal_load(&in2[(size_t)(8 + i) * HW2 + t]);

    float col[2], row[2];
#pragma unroll
    for (int j = 0; j < 2; ++j) {
        const float i0 = p[0][j], i1 = p[1][j], i2 = p[2][j], i3 = p[3][j];
        const float i4 = p[4][j], i5 = p[5][j], i6 = p[6][j], i7 = p[7][j];

        // s = i1 + SIN2*i2 - i3 ; c = ((i0 + COS1*i1) - i2) + COS3*i3
        // non-fused f32 ops: comparisons downstream are tie-sensitive
        float sc = __fsub_rn(__fadd_rn(i1, __fmul_rn(SIN2_C, i2)), i3);
        float cc = __fadd_rn(__fsub_rn(__fadd_rn(i0, __fmul_rn(COS1_C, i1)), i2),
                             __fmul_rn(COS3_C, i3));
        float sr = __fsub_rn(__fadd_rn(i5, __fmul_rn(SIN2_C, i6)), i7);
        float cr = __fadd_rn(__fsub_rn(__fadd_rn(i4, __fmul_rn(COS1_C, i5)), i6),
                             __fmul_rn(COS3_C, i7));

        float bgc = __fmul_rn(0.5f, __fsqrt_rn(__fadd_rn(__fmul_rn(sc, sc), __fmul_rn(cc, cc))));
        float bgr = __fmul_rn(0.5f, __fsqrt_rn(__fadd_rn(__fmul_rn(sr, sr), __fmul_rn(cr, cr))));
        float msk = (bgc > BG_THR_F || bgr > BG_THR_F) ? 1.0f : 0.0f;

        // pairwise (np-style) mean of the 8 phase-shift planes
        float thr = __fmul_rn(0.125f,
            __fadd_rn(__fadd_rn(__fadd_rn(i0, i1), __fadd_rn(i2, i3)),
                      __fadd_rn(__fadd_rn(i4, i5), __fadd_rn(i6, i7))));

        float psc = -atan2f(sc, cc);
        if (psc < 0.0f) psc = __fadd_rn(psc, TWO_PI_F);
        float psr = -atan2f(sr, cr);
        if (psr < 0.0f) psr = __fadd_rn(psr, TWO_PI_F);

        // graycode cumulative-XOR decode, ratio = {128,...,1}
        int cumc = 0, v2c = 0, k1c = 0;
        int cumr = 0, v2r = 0, k1r = 0;
#pragma unroll
        for (int i = 0; i < 8; ++i) {
            cumc ^= (g[i][j]     > thr) ? 1 : 0;
            cumr ^= (g[8 + i][j] > thr) ? 1 : 0;
            v2c += cumc << (7 - i);
            v2r += cumr << (7 - i);
            if (i < 7) { k1c += cumc << (6 - i); k1r += cumr << (6 - i); }
        }
        int k2c = (v2c + 1) >> 1;
        int k2r = (v2r + 1) >> 1;

        float ac;
        if (psc <= PI_HALF_F)      ac = __fmul_rn(TWO_PI_F, (float)k2c);
        else if (psc < PI3HALF_F)  ac = __fmul_rn(TWO_PI_F, (float)k1c);
        else                       ac = __fsub_rn(__fmul_rn(TWO_PI_F, (float)k2c), TWO_PI_F);
        float ar;
        if (psr <= PI_HALF_F)      ar = __fmul_rn(TWO_PI_F, (float)k2r);
        else if (psr < PI3HALF_F)  ar = __fmul_rn(TWO_PI_F, (float)k1r);
        else                       ar = __fsub_rn(__fmul_rn(TWO_PI_F, (float)k2r), TWO_PI_F);

        psc = __fadd_rn(psc, ac);
        psr = __fadd_rn(psr, ar);

        col[j] = __fmul_rn(__fmul_rn(psc, msk), SCALE_F);
        row[j] = __fmul_rn(__fmul_rn(psr, msk), SCALE_F);
    }

    // pixels 2t, 2t+1 -> out floats [4t .. 4t+3] == out4[t]
    f4 o = {col[0], row[0], col[1], row[1]};
    __builtin_nontemporal_store(o, &out4[t]);
}

extern "C" void kernel_launch(void* const* d_in, const int* in_sizes, int n_in,
                              void* d_out, int out_size, void* d_ws, size_t ws_size,
                              hipStream_t stream) {
    const float* img = (const float*)d_in[0];
    f4* out = (f4*)d_out;
    dim3 grid(HW2 / 256), block(256);   // 9792 blocks
    hipLaunchKernelGGL(cg_kernel, grid, block, 0, stream, img, out);
}